// Round 9
// baseline (266.404 us; speedup 1.0000x reference)
//
#include <hip/hip_runtime.h>
#include <cstdint>

namespace {

constexpr int W = 256;
constexpr int ITERS = 10;

// One block per (n,h) matrix, 1024 threads; thread (tr=tid>>5, tc=tid&31)
// owns the 8x8 tile rows [8tr,8tr+8) x cols [8tc,8tc+8) of E = exp(attn).
// Exp-domain Sinkhorn: no transcendentals in the loop.
//
// R7: E split 32 regs / 32 LDS (compiler pins 16-wave blocks to 64 VGPRs).
// R8: AGPR inline-asm pinning miscompiled (absmax 142) — abandoned.
// R9: (a) E-chunk LDS layout Echk[c][tid] — R7's tid*32 base made every
//     chunk access an 8-way bank conflict (SQ_LDS_BANK_CONFLICT 7.1M).
//     (b) row-direction reduction by in-half-wave shfl butterfly: eu stays
//     in registers, 2 barriers/iter instead of 4, one LDS reduce not two.
//     Dustbin scalars eu_W/ev_W carried redundantly per-thread.
__global__ __launch_bounds__(1024)
void sinkhorn_disp_kernel(
    const float* __restrict__ attn,
    const float* __restrict__ phi_p,
    float* __restrict__ out,
    int nh)
{
  __shared__ __align__(16) float4 Echk[8][1024];  // 128 KB: E rows 4..7
  __shared__ __align__(16) float fpart[16][260];  // 16.6 KB col-pass partials
  __shared__ __align__(16) float ev[W + 4];
  __shared__ __align__(16) float win[W][4];
  __shared__ int   jmax[W];
  __shared__ float seu_part[2][16];               // double-buffered (WAR race)
  __shared__ float sev_part[4];

  const int tid = threadIdx.x;
  const int tc  = tid & 31;
  const int tr  = tid >> 5;
  const int bid = blockIdx.x;
  const float ephi  = __expf(phi_p[0]);           // uniform scalar per thread
  const float inv2w = 1.0f / (2.0f * W);

  // ---- load + exp: rows 0..3 -> regs, rows 4..7 -> Echk (full-rate layout) ----
  float Er[4][8];
  {
    const float* src = attn + (size_t)bid * (W * W) + (size_t)(tr * 8) * W + tc * 8;
    #pragma unroll
    for (int a = 0; a < 4; ++a) {
      float4 x0 = *(const float4*)(src + a * W);
      float4 x1 = *(const float4*)(src + a * W + 4);
      Er[a][0] = __expf(x0.x); Er[a][1] = __expf(x0.y);
      Er[a][2] = __expf(x0.z); Er[a][3] = __expf(x0.w);
      Er[a][4] = __expf(x1.x); Er[a][5] = __expf(x1.y);
      Er[a][6] = __expf(x1.z); Er[a][7] = __expf(x1.w);
    }
    #pragma unroll
    for (int ap = 0; ap < 4; ++ap) {
      float4 x0 = *(const float4*)(src + (4 + ap) * W);
      float4 x1 = *(const float4*)(src + (4 + ap) * W + 4);
      Echk[2 * ap    ][tid] = make_float4(__expf(x0.x), __expf(x0.y), __expf(x0.z), __expf(x0.w));
      Echk[2 * ap + 1][tid] = make_float4(__expf(x1.x), __expf(x1.y), __expf(x1.z), __expf(x1.w));
    }
  }
  // eu state for this thread's 8 rows, in registers; dustbin scalars per-thread
  float eul[8];
  #pragma unroll
  for (int a = 0; a < 8; ++a) eul[a] = 1.0f;      // u0 = 0 -> eu = 1
  float euW = 1.0f;
  float evW = 0.0f;                               // set before first use
  if (tid < 16) seu_part[0][tid] = 16.0f;         // per-wave sum of eu=1 over 16 rows
  __syncthreads();

  for (int it = 0; it < ITERS; ++it) {
    // ---- column pass: cp[b] = sum_a E[a][b] * eu_a (eu from regs) ----
    {
      float cp[8];
      #pragma unroll
      for (int b = 0; b < 8; ++b) cp[b] = 0.0f;
      #pragma unroll
      for (int a = 0; a < 4; ++a) {
        float ua = eul[a];
        #pragma unroll
        for (int b = 0; b < 8; ++b) cp[b] = __builtin_fmaf(Er[a][b], ua, cp[b]);
      }
      #pragma unroll
      for (int ap = 0; ap < 4; ++ap) {
        float4 e0 = Echk[2 * ap][tid], e1 = Echk[2 * ap + 1][tid];
        float ua = eul[4 + ap];
        cp[0] = __builtin_fmaf(e0.x, ua, cp[0]);
        cp[1] = __builtin_fmaf(e0.y, ua, cp[1]);
        cp[2] = __builtin_fmaf(e0.z, ua, cp[2]);
        cp[3] = __builtin_fmaf(e0.w, ua, cp[3]);
        cp[4] = __builtin_fmaf(e1.x, ua, cp[4]);
        cp[5] = __builtin_fmaf(e1.y, ua, cp[5]);
        cp[6] = __builtin_fmaf(e1.z, ua, cp[6]);
        cp[7] = __builtin_fmaf(e1.w, ua, cp[7]);
      }
      // combine tr-parity pair (lane <-> lane^32, same wave)
      #pragma unroll
      for (int b = 0; b < 8; ++b) cp[b] += __shfl_xor(cp[b], 32, 64);
      if (!(tr & 1)) {
        float4* dst = (float4*)&fpart[tr >> 1][tc * 8];
        dst[0] = make_float4(cp[0], cp[1], cp[2], cp[3]);
        dst[1] = make_float4(cp[4], cp[5], cp[6], cp[7]);
      }
    }
    __syncthreads();                                   // barrier A
    // ---- column finalize: ev_j = nu_j / colsum_j; Sev partials ----
    if (tid < W) {
      float s = 0.0f;
      #pragma unroll
      for (int g = 0; g < 16; ++g) s += fpart[g][tid];  // stride-1, conflict-free
      s += ephi * euW;                                  // dustbin row term
      float e = inv2w / s;
      ev[tid] = e;
      float t = e;                                      // wave-sum of ev
      #pragma unroll
      for (int off = 32; off > 0; off >>= 1) t += __shfl_xor(t, off, 64);
      if ((tid & 63) == 0) sev_part[tid >> 6] = t;
    }
    __syncthreads();                                   // barrier B
    // ---- row pass: rp[a] = sum_b E[a][b] * ev_b; shfl-reduce over tc ----
    {
      float4 v0 = *(const float4*)&ev[tc * 8];
      float4 v1 = *(const float4*)&ev[tc * 8 + 4];
      float vl[8] = {v0.x, v0.y, v0.z, v0.w, v1.x, v1.y, v1.z, v1.w};
      float rp[8];
      #pragma unroll
      for (int a = 0; a < 8; ++a) rp[a] = 0.0f;
      #pragma unroll
      for (int a = 0; a < 4; ++a) {
        #pragma unroll
        for (int b = 0; b < 8; ++b) rp[a] = __builtin_fmaf(Er[a][b], vl[b], rp[a]);
      }
      #pragma unroll
      for (int ap = 0; ap < 4; ++ap) {
        float4 e0 = Echk[2 * ap][tid], e1 = Echk[2 * ap + 1][tid];
        rp[4 + ap] = e0.x * vl[0] + e0.y * vl[1] + e0.z * vl[2] + e0.w * vl[3]
                   + e1.x * vl[4] + e1.y * vl[5] + e1.z * vl[6] + e1.w * vl[7];
      }
      // butterfly over the 32 same-tr lanes (offsets 16..1 stay in half-wave)
      #pragma unroll
      for (int a = 0; a < 8; ++a) {
        #pragma unroll
        for (int off = 16; off > 0; off >>= 1) rp[a] += __shfl_xor(rp[a], off, 64);
      }
      // dustbin scalar chain (redundant per-thread, kept coherent)
      float seu_r = 0.0f;
      #pragma unroll
      for (int g = 0; g < 16; ++g) seu_r += seu_part[it & 1][g];
      evW = 0.5f / (ephi * (seu_r + euW));             // uses euW^(t-1)
      float sev_r = sev_part[0] + sev_part[1] + sev_part[2] + sev_part[3];
      euW = 0.5f / (ephi * (sev_r + evW));             // uses evW^(t)
      float dust = ephi * evW;
      #pragma unroll
      for (int a = 0; a < 8; ++a) eul[a] = inv2w / (rp[a] + dust);
      // Seu partial for next iteration (double-buffered: WAR-safe)
      float s = eul[0] + eul[1] + eul[2] + eul[3] + eul[4] + eul[5] + eul[6] + eul[7];
      s += __shfl_xor(s, 32, 64);
      if ((tid & 63) == 0) seu_part[(it + 1) & 1][tid >> 6] = s;
    }
  }

  // ---- finale: argmax over P[i][j] ~ E[i][j]*ev[j], 3-tap window ----
  if (tid < W) { win[tid][0] = 0.0f; win[tid][1] = 0.0f; win[tid][2] = 0.0f; }
  float vl[8];
  {
    float4 v0 = *(const float4*)&ev[tc * 8];
    float4 v1 = *(const float4*)&ev[tc * 8 + 4];
    vl[0] = v0.x; vl[1] = v0.y; vl[2] = v0.z; vl[3] = v0.w;
    vl[4] = v1.x; vl[5] = v1.y; vl[6] = v1.z; vl[7] = v1.w;
  }
  {
    #pragma unroll
    for (int a = 0; a < 8; ++a) {
      float m = -1.0f; int mj = 0;
      float e8[8];
      if (a < 4) {
        #pragma unroll
        for (int b = 0; b < 8; ++b) e8[b] = Er[a < 4 ? a : 0][b];
      } else {
        float4 e0 = Echk[2 * (a - 4)][tid], e1 = Echk[2 * (a - 4) + 1][tid];
        e8[0] = e0.x; e8[1] = e0.y; e8[2] = e0.z; e8[3] = e0.w;
        e8[4] = e1.x; e8[5] = e1.y; e8[6] = e1.z; e8[7] = e1.w;
      }
      #pragma unroll
      for (int b = 0; b < 8; ++b) {
        float vv = e8[b] * vl[b];                  // eu_i const per row: drop
        if (vv > m) { m = vv; mj = tc * 8 + b; }   // strict > : first max
      }
      // pack (value, first-index-wins); values > 0: float bits order-preserve
      unsigned long long best =
          (((unsigned long long)__float_as_uint(m)) << 32) |
          (unsigned)(65535 - mj);
      #pragma unroll
      for (int off = 16; off > 0; off >>= 1) {     // reduce within half-wave
        unsigned long long o = __shfl_xor(best, off, 64);
        best = (o > best) ? o : best;
      }
      if (tc == 0) jmax[tr * 8 + a] = 65535 - (int)(best & 0xffffffffull);
    }
  }
  __syncthreads();
  // window scatter: unique owner of column j writes P[i][j] (static E indices)
  {
    #pragma unroll
    for (int a = 0; a < 8; ++a) {
      int i  = tr * 8 + a;
      int jm = jmax[i];
      float e8[8];
      if (a < 4) {
        #pragma unroll
        for (int b = 0; b < 8; ++b) e8[b] = Er[a < 4 ? a : 0][b];
      } else {
        float4 e0 = Echk[2 * (a - 4)][tid], e1 = Echk[2 * (a - 4) + 1][tid];
        e8[0] = e0.x; e8[1] = e0.y; e8[2] = e0.z; e8[3] = e0.w;
        e8[4] = e1.x; e8[5] = e1.y; e8[6] = e1.z; e8[7] = e1.w;
      }
      #pragma unroll
      for (int b = 0; b < 8; ++b) {
        int k = (tc * 8 + b) - (jm - 1);
        if (k >= 0 && k < 3) {
          win[i][k] = e8[b] * vl[b] * eul[a] * (2.0f * W);
        }
      }
    }
  }
  __syncthreads();
  if (tid < W) {
    const int i  = tid;
    const int jm = jmax[i];
    float w0 = win[i][0], w1 = win[i][1], w2 = win[i][2];
    float norm0 = w0 + w1 + w2;
    float norm  = (norm0 < 0.1f) ? 1.0f : norm0;
    float p0 = fmaxf((float)(i - (jm - 1)), 0.0f);
    float p1 = fmaxf((float)(i - jm),       0.0f);
    float p2 = fmaxf((float)(i - (jm + 1)), 0.0f);
    float disp = (w0 / norm) * p0 + (w1 / norm) * p1 + (w2 / norm) * p2;
    float occ  = 1.0f - norm;
    out[(size_t)bid * W + i] = disp;
    out[(size_t)nh * W + (size_t)bid * W + i] = occ;
  }
}

} // namespace

extern "C" void kernel_launch(void* const* d_in, const int* in_sizes, int n_in,
                              void* d_out, int out_size, void* d_ws, size_t ws_size,
                              hipStream_t stream) {
  (void)n_in; (void)d_ws; (void)ws_size; (void)out_size;
  const float* attn = (const float*)d_in[0];
  const float* phi  = (const float*)d_in[1];
  float* out = (float*)d_out;
  const int nh = in_sizes[0] / (W * W);   // 4*120 = 480 matrices
  sinkhorn_disp_kernel<<<dim3(nh), dim3(1024), 0, stream>>>(attn, phi, out, nh);
}